// Round 10
// baseline (1179.496 us; speedup 1.0000x reference)
//
#include <hip/hip_runtime.h>

// LSTMDecoder: B=256, D=512, T=64, 2 layers. Persistent kernel, PLAIN launch.
// R10: chunked sentinel dataflow. h rotates through 128 per-stage buffers,
// pre-filled with 0xFFFFFFFF (fp16 NaN pair, unreachable from finite casts).
// Producers publish h via NON-RETURNING global_atomic_swap (executes at the
// MALL coherence point: visibility == 1 RT after issue, dword-atomic).
// Consumers: one speculative full burst, then PER-CHUNK (128 K) sentinel
// checks; only missing chunks are re-polled (4 loads = 1 KB/wave vs R9's
// 16 KB full-panel repolls that congested MALL), and MFMA proceeds on the
// chunks already present — a late producer gates 4 MFMAs, not the stage.
// Stale half (rot[s-2]) needs no check (validated by this WG's s-1 fresh
// check, ordered by the intra-WG barrier). No flags, no producer waits, no
// grid barriers => dispatch-order safe => plain launch.

#define BD    131072                      // B*D elements
#define SMEM_WBYTES 131072                // 2 layers * 32 gate-rows * 1024 K * 2B
#define SMEM_BYTES  (SMEM_WBYTES + 4 * 1056 * 4)   // + red[4][32][33] f32

#define WS_XINIT 4096
#define WS_ZERO  (WS_XINIT + BD * 2)
#define WS_ROT   (WS_ZERO + BD * 2)
#define ROT_BYTES ((size_t)BD * 2)        // 256 KB per stage buffer
#define WS_NEED  (WS_ROT + 128 * ROT_BYTES)   // ~32.5 MiB (R8 proved ws fits)

typedef _Float16 half8_t  __attribute__((ext_vector_type(8)));
typedef float    f32x16_t __attribute__((ext_vector_type(16)));
typedef float    f32x4_t  __attribute__((ext_vector_type(4)));
typedef unsigned uint4_t  __attribute__((ext_vector_type(4)));

__device__ __forceinline__ float sigmoidf_(float x) {
  float z = __expf(-fabsf(x));
  float s = 1.0f / (1.0f + z);
  return x >= 0.0f ? s : 1.0f - s;
}
__device__ __forceinline__ float tanhf_(float x) {
  float z = __expf(-2.0f * fabsf(x));
  float t = (1.0f - z) / (1.0f + z);
  return x >= 0.0f ? t : -t;
}

// system-scope (MALL-coherent) 16B load; caller must s_waitcnt vmcnt(0).
__device__ __forceinline__ f32x4_t load_cv16(const void* p) {
  f32x4_t r;
  asm volatile("global_load_dwordx4 %0, %1, off sc0 sc1"
               : "=v"(r) : "v"(p) : "memory");
  return r;
}
// non-returning atomic swap: executes AT the MALL — store visibility = 1 RT.
__device__ __forceinline__ void store_swap(unsigned* p, unsigned v) {
  asm volatile("global_atomic_swap %0, %1, off" :: "v"(p), "v"(v) : "memory");
}

__global__ void lstm_init(const float* __restrict__ h, char* __restrict__ ws) {
  int i = blockIdx.x * 256 + threadIdx.x;          // grid 2048*256 = 524288
  _Float16* xinit = (_Float16*)(ws + WS_XINIT);
  _Float16* zerob = (_Float16*)(ws + WS_ZERO);
  if (i < BD) {
    xinit[i] = (_Float16)h[i];
    zerob[i] = (_Float16)0.0f;
  }
  uint4_t* rot4 = (uint4_t*)(ws + WS_ROT);         // 33554432 B = 2097152 uint4
  uint4_t s4; s4[0] = 0xFFFFFFFFu; s4[1] = 0xFFFFFFFFu;
  s4[2] = 0xFFFFFFFFu; s4[3] = 0xFFFFFFFFu;
  for (int j = i; j < 2097152; j += 524288) rot4[j] = s4;
}

__global__ void __launch_bounds__(256, 1) lstm_persist(
    const float* __restrict__ Wih0, const float* __restrict__ Whh0,
    const float* __restrict__ bih0, const float* __restrict__ bhh0,
    const float* __restrict__ Wih1, const float* __restrict__ Whh1,
    const float* __restrict__ bih1, const float* __restrict__ bhh1,
    float* __restrict__ out, char* __restrict__ ws)
{
  extern __shared__ char smem[];
  float* red = (float*)(smem + SMEM_WBYTES);   // red[4 waves][32 rows][33 pad]
  const _Float16* xinit = (const _Float16*)(ws + WS_XINIT);
  const _Float16* zerob = (const _Float16*)(ws + WS_ZERO);
  char* rot = ws + WS_ROT;

  const int tid = threadIdx.x;
  const int l = tid & 63;
  const int w = tid >> 6;
  const int bid = blockIdx.x;
  const int bb = (bid & 7) >> 1;                       // 0..3 batch group
  const int db = ((bid >> 3) << 1) | (bid & 1);        // 0..63 d block
  const int b0 = bb << 6;                              // 64 batch rows
  const int d0 = db << 3;                              // 8 d values

  // ---- stage weights (fp32 -> fp16) into LDS in MFMA B-fragment order ----
#pragma unroll
  for (int L = 0; L < 2; ++L) {
    for (int it = 0; it < 16; ++it) {
      int slot = it * 256 + tid;                 // 0..4095
      int s2 = slot >> 6, lane = slot & 63;
      int khalf = s2 >> 5, ks = s2 & 31;
      int kg = lane >> 5, nl = lane & 31;
      int ng = ((nl >> 3) << 9) + d0 + (nl & 7); // gate*512 + d0 + j
      int col = ks * 16 + kg * 8;
      const float* srcb = khalf ? (L ? Whh1 : Whh0) : (L ? Wih1 : Wih0);
      const float* src = srcb + (size_t)ng * 512 + col;
      half8_t hv;
#pragma unroll
      for (int j = 0; j < 8; ++j) hv[j] = (_Float16)src[j];
      *(half8_t*)(smem + (size_t)L * 65536 + (size_t)slot * 16) = hv;
    }
  }

  // ---- bias (b_ih+b_hh) for this thread's two d values (j0, j0+1) ----
  const int cbl = tid >> 2;            // batch row (within group) in cell phase
  const int j0 = (tid & 3) << 1;       // even d offset
  float bias0[4][2], bias1[4][2];
#pragma unroll
  for (int g = 0; g < 4; ++g) {
#pragma unroll
    for (int p = 0; p < 2; ++p) {
      int ng = (g << 9) + d0 + j0 + p;
      bias0[g][p] = bih0[ng] + bhh0[ng];
      bias1[g][p] = bih1[ng] + bhh1[ng];
    }
  }
  float c0s[2] = {0.0f, 0.0f}, c1s[2] = {0.0f, 0.0f};
  __syncthreads();

  // ---- 128 sequential stages: s even = layer0, odd = layer1 ----
  for (int s = 0; s < 128; ++s) {
    const int t = s >> 1;
    const int layer = s & 1;
    const _Float16* fresh = (s == 0) ? xinit
                          : (const _Float16*)(rot + (size_t)(s - 1) * ROT_BYTES);
    const _Float16* stale = (s <= 1) ? zerob
                          : (const _Float16*)(rot + (size_t)(s - 2) * ROT_BYTES);
    _Float16* hout = (_Float16*)(rot + (size_t)s * ROT_BYTES);

    // ---- GEMM: wave w: M-tile = w&1 (32 b-rows), input-half = w>>1 ----
    const _Float16* asrc = (w >= 2) ? stale : fresh;
    const char* ap = (const char*)(asrc + (size_t)(b0 + ((w & 1) << 5) + (l & 31)) * 512
                                        + ((l >> 5) << 3));
    const bool needcheck = (w < 2) && (s > 0);
    const int boff = layer * 65536 + ((w >> 1) * 32768) + l * 16;

    f32x16_t acc0, acc1;
#pragma unroll
    for (int r = 0; r < 16; ++r) { acc0[r] = 0.0f; acc1[r] = 0.0f; }

#pragma unroll
    for (int half = 0; half < 2; ++half) {
      const char* hp = ap + half * 512;
      const int bo = boff + half * 16384;
      f32x4_t va[16];
#pragma unroll
      for (int j = 0; j < 16; ++j) va[j] = load_cv16(hp + 32 * j);
      asm volatile("s_waitcnt vmcnt(0)" ::: "memory");

      if (needcheck) {
        // per-chunk sentinel check; retry ONLY missing chunks (1 KB/wave)
        unsigned okm = 0u;
#pragma unroll
        for (int c = 0; c < 4; ++c) {
          unsigned mx = 0u;
#pragma unroll
          for (int j = 0; j < 4; ++j)
#pragma unroll
            for (int d = 0; d < 4; ++d) {
              unsigned u = __float_as_uint(va[4 * c + j][d]);
              mx = (u > mx) ? u : mx;
            }
          okm |= __all(mx != 0xFFFFFFFFu) ? (1u << c) : 0u;
        }
#pragma unroll
        for (int c = 0; c < 4; ++c) {
          if (!(okm & (1u << c))) {
            while (true) {
#pragma unroll
              for (int j = 0; j < 4; ++j)
                va[4 * c + j] = load_cv16(hp + (4 * c + j) * 32);
              asm volatile("s_waitcnt vmcnt(0)" ::: "memory");
              unsigned mx = 0u;
#pragma unroll
              for (int j = 0; j < 4; ++j)
#pragma unroll
                for (int d = 0; d < 4; ++d) {
                  unsigned u = __float_as_uint(va[4 * c + j][d]);
                  mx = (u > mx) ? u : mx;
                }
              if (__all(mx != 0xFFFFFFFFu)) break;
              asm volatile("s_sleep 2");
            }
          }
          // consume chunk c immediately (2 k-steps, 4 MFMAs)
#pragma unroll
          for (int k2 = 0; k2 < 2; ++k2) {
            const int bos = bo + (2 * c + k2) * 2048;
            half8_t a0  = __builtin_bit_cast(half8_t, va[4 * c + 2 * k2]);
            half8_t a1  = __builtin_bit_cast(half8_t, va[4 * c + 2 * k2 + 1]);
            half8_t bv0 = *(const half8_t*)(smem + bos);
            half8_t bv1 = *(const half8_t*)(smem + bos + 1024);
            acc0 = __builtin_amdgcn_mfma_f32_32x32x16_f16(a0, bv0, acc0, 0, 0, 0);
            acc1 = __builtin_amdgcn_mfma_f32_32x32x16_f16(a1, bv1, acc1, 0, 0, 0);
          }
        }
      } else {
#pragma unroll
        for (int ks = 0; ks < 8; ++ks) {
          const int bos = bo + ks * 2048;
          half8_t a0  = __builtin_bit_cast(half8_t, va[2 * ks]);
          half8_t a1  = __builtin_bit_cast(half8_t, va[2 * ks + 1]);
          half8_t bv0 = *(const half8_t*)(smem + bos);
          half8_t bv1 = *(const half8_t*)(smem + bos + 1024);
          acc0 = __builtin_amdgcn_mfma_f32_32x32x16_f16(a0, bv0, acc0, 0, 0, 0);
          acc1 = __builtin_amdgcn_mfma_f32_32x32x16_f16(a1, bv1, acc1, 0, 0, 0);
        }
      }
    }

    // ---- C frags -> LDS red[w][row][33] (row = (r&3)+8*(r>>2)+4*(l>>5)) ----
    {
      float* redw = red + w * 1056 + (l & 31);
      const int rbase = (l >> 5) << 2;
#pragma unroll
      for (int r = 0; r < 16; ++r) {
        int row = (r & 3) + ((r >> 2) << 3) + rbase;
        redw[row * 33] = acc0[r] + acc1[r];
      }
    }
    __syncthreads();

    // ---- cell update: thread owns (cbl, j0) and (cbl, j0+1); c in regs ----
    {
      const int base = (cbl >> 5) * 1056 + (cbl & 31) * 33 + j0;
      float hv[2];
#pragma unroll
      for (int p = 0; p < 2; ++p) {
        float vi = red[base + p]      + red[base + 2112 + p]      + (layer ? bias1[0][p] : bias0[0][p]);
        float vf = red[base + 8 + p]  + red[base + 2112 + 8 + p]  + (layer ? bias1[1][p] : bias0[1][p]);
        float vg = red[base + 16 + p] + red[base + 2112 + 16 + p] + (layer ? bias1[2][p] : bias0[2][p]);
        float vo = red[base + 24 + p] + red[base + 2112 + 24 + p] + (layer ? bias1[3][p] : bias0[3][p]);
        float iv = sigmoidf_(vi), fv = sigmoidf_(vf);
        float gv = tanhf_(vg),    ov = sigmoidf_(vo);
        float cold = layer ? c1s[p] : c0s[p];
        float c = fv * cold + iv * gv;
        if (layer) c1s[p] = c; else c0s[p] = c;
        hv[p] = ov * tanhf_(c);
      }
      const int gidx = (b0 + cbl) * 512 + d0 + j0;
      unsigned hu = ((unsigned)__builtin_bit_cast(unsigned short, (_Float16)hv[0])) |
                    ((unsigned)__builtin_bit_cast(unsigned short, (_Float16)hv[1]) << 16);
      store_swap((unsigned*)&hout[gidx], hu);   // visible at MALL ~1 RT
      if (layer) {
        float* op = out + (size_t)t * BD + gidx;
        op[0] = hv[0]; op[1] = hv[1];
      }
    }
    __syncthreads();   // red[] reuse ordering only — no drain, no flag
  }
}

extern "C" void kernel_launch(void* const* d_in, const int* in_sizes, int n_in,
                              void* d_out, int out_size, void* d_ws, size_t ws_size,
                              hipStream_t stream) {
  const float* h    = (const float*)d_in[0];
  // d_in[1] = T (== 64, compile-time)
  const float* Wih0 = (const float*)d_in[2];
  const float* Whh0 = (const float*)d_in[3];
  const float* bih0 = (const float*)d_in[4];
  const float* bhh0 = (const float*)d_in[5];
  const float* Wih1 = (const float*)d_in[6];
  const float* Whh1 = (const float*)d_in[7];
  const float* bih1 = (const float*)d_in[8];
  const float* bhh1 = (const float*)d_in[9];
  float* out = (float*)d_out;
  char* ws = (char*)d_ws;

  if (ws_size < (size_t)WS_NEED) return;   // fail loud (R8 proved it fits)

  hipFuncSetAttribute((const void*)lstm_persist,
                      hipFuncAttributeMaxDynamicSharedMemorySize, SMEM_BYTES);

  lstm_init<<<2048, 256, 0, stream>>>(h, ws);

  lstm_persist<<<256, 256, SMEM_BYTES, stream>>>(Wih0, Whh0, bih0, bhh0,
                                                 Wih1, Whh1, bih1, bhh1,
                                                 out, ws);
}